// Round 1
// baseline (7359.384 us; speedup 1.0000x reference)
//
#include <hip/hip_runtime.h>
#include <hip/hip_bf16.h>

using bf16 = __hip_bfloat16;
typedef short short8 __attribute__((ext_vector_type(8)));
typedef float floatx4 __attribute__((ext_vector_type(4)));

#define B_   16
#define C_   768
#define NP_  196
#define H_   12
#define NPNP 38416   // 196*196

static __device__ __forceinline__ float b2f(bf16 v) { return __bfloat162float(v); }
static __device__ __forceinline__ unsigned short f2bfbits(float f) {
    bf16 t = __float2bfloat16(f);
    return *(unsigned short*)&t;
}

// ---------------------------------------------------------------------------
// Batched MFMA GEMM:  C[z][m][n] = act( scale * sum_k A[z][m][k]*W[z][n][k] + bias[n] )
// A bf16 row-major. W bf16 (wfp=0) or fp32 (wfp=1, converted to bf16 in
// staging). bias fp32 or null. K multiple of 32, lda/ldw multiple of 8.
// Batch offsets are two-level for A, W and C:  off = (z/BI)*so + (z%BI)*si.
// Epilogue: if resg != null, C[m][n] += resg[n] * v  (fp32 read-mod-write);
// else writes fp32 (outbf=0) or bf16 (outbf=1).
// Tile 128x128, 256 thr = 4 waves (2x2), each wave 4x4 of 16x16x32 MFMA.
// ---------------------------------------------------------------------------
__global__ __launch_bounds__(256)
void k_mgemm(const bf16* __restrict__ A, long long sAo, long long sAi, int ABI, int lda,
             const void* __restrict__ W, long long sWo, long long sWi, int WBI, int ldw, int wfp,
             char* __restrict__ Cb, long long sCo, long long sCi, int CBI, int ldc,
             const float* __restrict__ bias, const float* __restrict__ resg,
             int M, int N, int K, float scale, int act, int outbf)
{
    __shared__ unsigned short As[128 * 40];   // stride 40 elems (80B)
    __shared__ unsigned short Ws[128 * 40];

    const int z = blockIdx.z;
    const long long aoff = (long long)(z / ABI) * sAo + (long long)(z % ABI) * sAi;
    const long long woff = (long long)(z / WBI) * sWo + (long long)(z % WBI) * sWi;
    const unsigned short* Ag = (const unsigned short*)A + aoff;

    const int tid = threadIdx.x;
    const int lane = tid & 63, w = tid >> 6;
    const int wm = w >> 1, wn = w & 1;
    const int p = lane & 15, q = lane >> 4;
    const int bm = blockIdx.y * 128, bn = blockIdx.x * 128;

    const int srow = tid >> 2;            // 0..63
    const int c8 = (tid & 3) * 8;         // k-chunk offset in elements

    floatx4 acc[4][4] = {};

    for (int k0 = 0; k0 < K; k0 += 32) {
        __syncthreads();
#pragma unroll
        for (int it = 0; it < 2; it++) {
            int r = srow + it * 64;
            int am = bm + r; am = (am < M) ? am : (M - 1);
            short8 av = *(const short8*)(Ag + (size_t)am * lda + k0 + c8);
            *(short8*)(&As[r * 40 + c8]) = av;
            int wr = bn + r; wr = (wr < N) ? wr : (N - 1);
            if (wfp) {
                const float* wp = (const float*)W + woff
                                  + (size_t)wr * ldw + k0 + c8;
                floatx4 w0 = *(const floatx4*)wp;
                floatx4 w1 = *(const floatx4*)(wp + 4);
                unsigned short* d = &Ws[r * 40 + c8];
#pragma unroll
                for (int j = 0; j < 4; j++) d[j]     = f2bfbits(w0[j]);
#pragma unroll
                for (int j = 0; j < 4; j++) d[4 + j] = f2bfbits(w1[j]);
            } else {
                const unsigned short* wp = (const unsigned short*)W
                                           + woff + (size_t)wr * ldw + k0 + c8;
                *(short8*)(&Ws[r * 40 + c8]) = *(const short8*)wp;
            }
        }
        __syncthreads();
        short8 af[4], wf[4];
#pragma unroll
        for (int i = 0; i < 4; i++)
            af[i] = *(const short8*)(&As[(wm * 64 + i * 16 + p) * 40 + q * 8]);
#pragma unroll
        for (int j = 0; j < 4; j++)
            wf[j] = *(const short8*)(&Ws[(wn * 64 + j * 16 + p) * 40 + q * 8]);
#pragma unroll
        for (int i = 0; i < 4; i++)
#pragma unroll
            for (int j = 0; j < 4; j++)
                acc[i][j] = __builtin_amdgcn_mfma_f32_16x16x32_bf16(af[i], wf[j], acc[i][j], 0, 0, 0);
    }

    const long long coff = (long long)(z / CBI) * sCo + (long long)(z % CBI) * sCi;
    float* Cf = (float*)Cb + coff;
    bf16*  Ch = (bf16*)Cb + coff;
#pragma unroll
    for (int i = 0; i < 4; i++) {
#pragma unroll
        for (int r = 0; r < 4; r++) {
            int gm = bm + wm * 64 + i * 16 + q * 4 + r;
            if (gm >= M) continue;
#pragma unroll
            for (int j = 0; j < 4; j++) {
                int gn = bn + wn * 64 + j * 16 + p;
                if (gn >= N) continue;
                float v = acc[i][j][r] * scale;
                if (bias) v += bias[gn];
                if (act) v = 0.5f * v * (1.0f + erff(v * 0.70710678118654752f));
                if (resg)       Cf[(size_t)gm * ldc + gn] += resg[gn] * v;
                else if (outbf) Ch[(size_t)gm * ldc + gn] = __float2bfloat16(v);
                else            Cf[(size_t)gm * ldc + gn] = v;
            }
        }
    }
}

// ---------------------------------------------------------------------------
__global__ __launch_bounds__(256)
void k_patch_gather(const float* __restrict__ x, bf16* __restrict__ p)
{
    int idx = blockIdx.x * 256 + threadIdx.x;            // 2,408,448
    int k = idx % 768;
    int n = (idx / 768) % NP_;
    int b = idx / (768 * NP_);
    int c = k >> 8, r = k & 255;
    int py = r >> 4, px = r & 15;
    int gy = n / 14, gx = n % 14;
    p[idx] = __float2bfloat16(x[(((size_t)b * 3 + c) * 224 + gy * 16 + py) * 224 + gx * 16 + px]);
}

__global__ __launch_bounds__(256)
void k_addpos(float* __restrict__ h, const float* __restrict__ pos)
{
    int idx = blockIdx.x * 256 + threadIdx.x;            // 2,408,448
    h[idx] += pos[idx % (NP_ * C_)];
}

// LayerNorm over C=768: fp32 in -> bf16 out. One block per row.
__device__ __forceinline__ void ln_row(const float* __restrict__ x,
                                       const float* __restrict__ w,
                                       const float* __restrict__ b,
                                       bf16* __restrict__ y, int t,
                                       float* red, float* stat)
{
    float a0 = x[t], a1 = x[t + 256], a2 = x[t + 512];
    float s = a0 + a1 + a2;
#pragma unroll
    for (int off = 32; off > 0; off >>= 1) s += __shfl_down(s, off);
    if ((t & 63) == 0) red[t >> 6] = s;
    __syncthreads();
    if (t == 0) stat[0] = (red[0] + red[1] + red[2] + red[3]) * (1.f / 768.f);
    __syncthreads();
    float m = stat[0];
    float d0 = a0 - m, d1 = a1 - m, d2 = a2 - m;
    float s2 = d0 * d0 + d1 * d1 + d2 * d2;
#pragma unroll
    for (int off = 32; off > 0; off >>= 1) s2 += __shfl_down(s2, off);
    if ((t & 63) == 0) red[t >> 6] = s2;
    __syncthreads();
    if (t == 0) stat[1] = rsqrtf((red[0] + red[1] + red[2] + red[3]) * (1.f / 768.f) + 1e-6f);
    __syncthreads();
    float r = stat[1];
    y[t]       = __float2bfloat16(d0 * r * w[t]       + b[t]);
    y[t + 256] = __float2bfloat16(d1 * r * w[t + 256] + b[t + 256]);
    y[t + 512] = __float2bfloat16(d2 * r * w[t + 512] + b[t + 512]);
}

__global__ __launch_bounds__(256)
void k_ln(const float* __restrict__ X, const float* __restrict__ w,
          const float* __restrict__ b, bf16* __restrict__ Y)
{
    __shared__ float red[4];
    __shared__ float stat[2];
    int row = blockIdx.x;
    ln_row(X + (size_t)row * C_, w, b, Y + (size_t)row * C_, threadIdx.x, red, stat);
}

__global__ __launch_bounds__(256)
void k_ln_cat(const float* __restrict__ cls, const float* __restrict__ h,
              const float* __restrict__ w, const float* __restrict__ b,
              bf16* __restrict__ Y)
{
    __shared__ float red[4];
    __shared__ float stat[2];
    int row = blockIdx.x;
    int bb = row / 197, tkn = row % 197;
    const float* src = (tkn == 0) ? (cls + (size_t)bb * C_)
                                  : (h + ((size_t)bb * NP_ + (tkn - 1)) * C_);
    ln_row(src, w, b, Y + (size_t)row * C_, threadIdx.x, red, stat);
}

// V transposed: VT[z][d][m] (m padded 196->224 with 0)
__global__ __launch_bounds__(256)
void k_splitv(const bf16* __restrict__ qkv, bf16* __restrict__ VT)
{
    int idx = blockIdx.x * 256 + threadIdx.x;            // 2,752,512
    int m = idx % 224;
    int rest = idx / 224;
    int d = rest & 63, zz = rest >> 6;
    int b = zz / H_, hh = zz % H_;
    bf16 v = __float2bfloat16(0.f);
    if (m < NP_) v = qkv[((size_t)b * NP_ + m) * 2304 + 1536 + hh * 64 + d];
    VT[idx] = v;
}

// ---------------------------------------------------------------------------
// Fused pre-mix + softmax + post-mix.
// Reads raw S fp32 [b*12+h][196][196] ONCE, applies pre-softmax talking-heads
// mix (12x12 over head axis), softmax over m, post-softmax mix, writes
// P bf16 [b*12+g][196][224] (m tail 196..223 pre-zeroed elsewhere).
// One block per (b, n): 3136 blocks x 256 threads, thread = column m.
// ---------------------------------------------------------------------------
__global__ __launch_bounds__(256)
void k_attn_mix(const float* __restrict__ S, const float* __restrict__ plw,
                const float* __restrict__ plb, const float* __restrict__ pww,
                const float* __restrict__ pwb, bf16* __restrict__ P)
{
    __shared__ float wpre[144], wpost[144], bpre[12], bpost[12];
    __shared__ float red[4][12];
    int tid = threadIdx.x;
    if (tid < 144) { wpre[tid] = plw[tid]; wpost[tid] = pww[tid]; }
    if (tid < 12)  { bpre[tid] = plb[tid]; bpost[tid] = pwb[tid]; }
    __syncthreads();
    int b = blockIdx.x / NP_, n = blockIdx.x % NP_;
    int m = tid;
    bool on = (m < NP_);
    const float* p0 = S + ((size_t)b * H_ * NP_ + n) * NP_ + (on ? m : 0);
    float v[12];
#pragma unroll
    for (int h = 0; h < 12; h++) v[h] = p0[(size_t)h * NPNP];
    // pre-softmax head mix
    float s[12];
#pragma unroll
    for (int g = 0; g < 12; g++) {
        float a = bpre[g];
#pragma unroll
        for (int h = 0; h < 12; h++) a += wpre[g * 12 + h] * v[h];
        s[g] = on ? a : -1e30f;
    }
    // row max per head (across 256 threads)
    int wv = tid >> 6, ln = tid & 63;
    float mx[12];
#pragma unroll
    for (int g = 0; g < 12; g++) {
        float x = s[g];
#pragma unroll
        for (int off = 32; off > 0; off >>= 1) x = fmaxf(x, __shfl_down(x, off));
        mx[g] = x;
    }
    if (ln == 0) {
#pragma unroll
        for (int g = 0; g < 12; g++) red[wv][g] = mx[g];
    }
    __syncthreads();
#pragma unroll
    for (int g = 0; g < 12; g++)
        mx[g] = fmaxf(fmaxf(red[0][g], red[1][g]), fmaxf(red[2][g], red[3][g]));
    __syncthreads();
    // exp + row sum per head
    float e[12], sm[12];
#pragma unroll
    for (int g = 0; g < 12; g++) {
        e[g] = on ? expf(s[g] - mx[g]) : 0.f;
        float x = e[g];
#pragma unroll
        for (int off = 32; off > 0; off >>= 1) x += __shfl_down(x, off);
        sm[g] = x;
    }
    if (ln == 0) {
#pragma unroll
        for (int g = 0; g < 12; g++) red[wv][g] = sm[g];
    }
    __syncthreads();
#pragma unroll
    for (int g = 0; g < 12; g++) {
        float t = (red[0][g] + red[1][g]) + (red[2][g] + red[3][g]);
        e[g] *= 1.0f / t;
    }
    // post-softmax head mix + write P
    if (on) {
        size_t base = ((size_t)b * H_ * NP_ + n) * 224 + m;
#pragma unroll
        for (int g = 0; g < 12; g++) {
            float a = bpost[g];
#pragma unroll
            for (int h = 0; h < 12; h++) a += wpost[g * 12 + h] * e[h];
            P[base + (size_t)g * NP_ * 224] = __float2bfloat16(a);
        }
    }
}

// class-attention: q fp32 [B,C], k/v bf16 [B*197,C] -> o bf16 [B,C]
__global__ __launch_bounds__(256)
void k_ca_attn(const float* __restrict__ q, const bf16* __restrict__ kb,
               const bf16* __restrict__ vb, bf16* __restrict__ o)
{
    __shared__ float sc[200];
    __shared__ float qs[64];
    __shared__ float inv_s;
    int b = blockIdx.x / H_, hh = blockIdx.x % H_;
    int t = threadIdx.x;
    if (t < 64) qs[t] = q[b * C_ + hh * 64 + t] * 0.125f;
    __syncthreads();
    if (t < 197) {
        const bf16* kp = kb + ((size_t)b * 197 + t) * C_ + hh * 64;
        float s = 0.f;
#pragma unroll 8
        for (int d = 0; d < 64; d++) s += qs[d] * b2f(kp[d]);
        sc[t] = s;
    }
    __syncthreads();
    if (t == 0) {
        float mx = -1e30f;
        for (int m = 0; m < 197; m++) mx = fmaxf(mx, sc[m]);
        float sum = 0.f;
        for (int m = 0; m < 197; m++) { float e = expf(sc[m] - mx); sc[m] = e; sum += e; }
        inv_s = 1.0f / sum;
    }
    __syncthreads();
    if (t < 64) {
        const bf16* vp = vb + (size_t)b * 197 * C_ + hh * 64 + t;
        float acc = 0.f;
        for (int m = 0; m < 197; m++) acc += sc[m] * b2f(vp[(size_t)m * C_]);
        o[b * C_ + hh * 64 + t] = __float2bfloat16(acc * inv_s);
    }
}

__global__ __launch_bounds__(256)
void k_bcast_cls(const float* __restrict__ ct, float* __restrict__ cls)
{
    int i = blockIdx.x * 256 + threadIdx.x;              // 12288
    if (i < B_ * C_) cls[i] = ct[i % C_];
}

__global__ __launch_bounds__(256)
void k_zero(float* __restrict__ p, int n)
{
    int i = blockIdx.x * 256 + threadIdx.x;
    if (i < n) p[i] = 0.f;
}

// ---------------------------------------------------------------------------
extern "C" void kernel_launch(void* const* d_in, const int* in_sizes, int n_in,
                              void* d_out, int out_size, void* d_ws, size_t ws_size,
                              hipStream_t stream)
{
    const float* in_x    = (const float*)d_in[0];
    const float* patch_w = (const float*)d_in[1];
    const float* patch_b = (const float*)d_in[2];
    const float* cls_tok = (const float*)d_in[3];
    const float* pos_emb = (const float*)d_in[4];
    const float* n1w = (const float*)d_in[5],  *n1b = (const float*)d_in[6];
    const float* qkvw = (const float*)d_in[7], *qkvb = (const float*)d_in[8];
    const float* plw = (const float*)d_in[9],  *plb = (const float*)d_in[10];
    const float* pww = (const float*)d_in[11], *pwb = (const float*)d_in[12];
    const float* projw = (const float*)d_in[13], *projb = (const float*)d_in[14];
    const float* n2w = (const float*)d_in[15], *n2b = (const float*)d_in[16];
    const float* f1w = (const float*)d_in[17], *f1b = (const float*)d_in[18];
    const float* f2w = (const float*)d_in[19], *f2b = (const float*)d_in[20];
    const float* g1 = (const float*)d_in[21],  *g2 = (const float*)d_in[22];
    const float* tn1w = (const float*)d_in[23], *tn1b = (const float*)d_in[24];
    const float* tqw = (const float*)d_in[25], *tqb = (const float*)d_in[26];
    const float* tkw = (const float*)d_in[27], *tkb = (const float*)d_in[28];
    const float* tvw = (const float*)d_in[29], *tvb = (const float*)d_in[30];
    const float* tprojw = (const float*)d_in[31], *tprojb = (const float*)d_in[32];
    const float* tn2w = (const float*)d_in[33], *tn2b = (const float*)d_in[34];
    const float* tf1w = (const float*)d_in[35], *tf1b = (const float*)d_in[36];
    const float* tf2w = (const float*)d_in[37], *tf2b = (const float*)d_in[38];
    const float* tg1 = (const float*)d_in[39], *tg2 = (const float*)d_in[40];
    const float* normw = (const float*)d_in[41], *normb = (const float*)d_in[42];
    const float* headw = (const float*)d_in[43], *headb = (const float*)d_in[44];
    (void)in_sizes; (void)n_in; (void)out_size; (void)ws_size;

    const int M = B_ * NP_;          // 3136
    char* wsb = (char*)d_ws;
    // ---- workspace layout (bytes) ----
    float* h    = (float*)(wsb + 0);                 //  9,633,792 B fp32 residual
    bf16*  yB   = (bf16*)(wsb + 9633792);            //  4,816,896 B bf16 LN out
    char*  BIG  = wsb + 14450688;                    // 29,503,488 B multi-use
    bf16*  VT   = (bf16*)(wsb + 53587968);           //  5,505,024
    bf16*  P    = (bf16*)(wsb + 59092992);           // 16,859,136
    bf16*  oB   = (bf16*)(wsb + 75952128);           //  4,816,896 -> end 80,769,024
    // BIG aliases
    bf16*  pbuf = (bf16*)BIG;                        // patches [3136x768]
    bf16*  qkvB = (bf16*)BIG;                        // [3136x2304] bf16
    float* S    = (float*)BIG;                       // [192][196][196] fp32
    bf16*  hidB = (bf16*)BIG;                        // [3136x3072] bf16
    // class-attention aliases
    bf16*  u    = (bf16*)BIG;                        // [3152x768]
    bf16*  kbuf = (bf16*)(BIG + 5242880);
    bf16*  vbuf = (bf16*)(BIG + 10485760);
    float* qbuf = (float*)(wsb + 43954176);          // 49,152
    bf16*  ca_o = (bf16*)(wsb + 43954176 + 65536);
    bf16*  clsB = (bf16*)(wsb + 43954176 + 262144);
    bf16*  cmlp = (bf16*)(wsb + 43954176 + 327680);
    float* cls  = (float*)(wsb + 59092992);          // alias P (dead in CA phase)

    auto mg = [&](const bf16* A, long long sAo, long long sAi, int ABI, int lda,
                  const void* Wt, long long sWo, long long sWi, int WBI, int ldw, int wfp,
                  void* Cc, long long sCo, long long sCi, int CBI, int ldc,
                  const float* bias, const float* resg, int Mm, int Nn, int Kk,
                  float scale, int act, int outbf, int batch) {
        dim3 g((Nn + 127) / 128, (Mm + 127) / 128, batch);
        k_mgemm<<<g, 256, 0, stream>>>(A, sAo, sAi, ABI, lda, Wt, sWo, sWi, WBI, ldw, wfp,
                                       (char*)Cc, sCo, sCi, CBI, ldc, bias, resg,
                                       Mm, Nn, Kk, scale, act, outbf);
    };

    // zero P once (tail columns 196..223 must be 0; ws re-poisoned every call)
    k_zero<<<(4214784 + 255) / 256, 256, 0, stream>>>((float*)P, 4214784);

    // ---- patch embed -------------------------------------------------------
    k_patch_gather<<<9408, 256, 0, stream>>>(in_x, pbuf);
    mg(pbuf, 0, 0, 1, 768, patch_w, 0, 0, 1, 768, 1, h, 0, 0, 1, 768,
       patch_b, nullptr, M, 768, 768, 1.f, 0, 0, 1);
    k_addpos<<<9408, 256, 0, stream>>>(h, pos_emb);

    // ---- 12 talking-heads blocks ------------------------------------------
    for (int L = 0; L < 12; L++) {
        size_t lC = (size_t)L * C_;
        k_ln<<<M, 256, 0, stream>>>(h, n1w + lC, n1b + lC, yB);
        mg(yB, 0, 0, 1, 768, qkvw + (size_t)L * 2304 * 768, 0, 0, 1, 768, 1,
           qkvB, 0, 0, 1, 2304, qkvb + (size_t)L * 2304, nullptr,
           M, 2304, 768, 1.f, 0, 1, 1);
        k_splitv<<<10752, 256, 0, stream>>>(qkvB, VT);
        // S[z] = 0.125 * Q[z] @ K[z]^T  directly from qkvB (z = b*12+h)
        mg(qkvB, (long long)NP_ * 2304, 64, H_, 2304,
           qkvB + 768, (long long)NP_ * 2304, 64, H_, 2304, 0,
           S, NPNP, 0, 1, 196, nullptr, nullptr,
           196, 196, 64, 0.125f, 0, 0, 192);
        // fused pre-mix + softmax + post-mix -> P bf16 [z][196][224]
        k_attn_mix<<<M, 256, 0, stream>>>(S, plw + L * 144, plb + L * 12,
                                          pww + L * 144, pwb + L * 12, P);
        // o[b][n][h*64+d] = P[z] @ V[z]  (K=224 zero-padded)
        mg(P, 43904, 0, 1, 224, VT, 14336, 0, 1, 224, 0,
           oB, 150528, 64, H_, 768, nullptr, nullptr,
           196, 64, 224, 1.f, 0, 1, 192);
        // proj with fused residual: h += g1 * (oB @ projw^T + projb)
        mg(oB, 0, 0, 1, 768, projw + (size_t)L * 768 * 768, 0, 0, 1, 768, 1,
           h, 0, 0, 1, 768, projb + lC, g1 + lC, M, 768, 768, 1.f, 0, 0, 1);
        k_ln<<<M, 256, 0, stream>>>(h, n2w + lC, n2b + lC, yB);
        mg(yB, 0, 0, 1, 768, f1w + (size_t)L * 3072 * 768, 0, 0, 1, 768, 1,
           hidB, 0, 0, 1, 3072, f1b + (size_t)L * 3072, nullptr,
           M, 3072, 768, 1.f, 1, 1, 1);
        // f2 with fused residual: h += g2 * (hidB @ f2w^T + f2b)
        mg(hidB, 0, 0, 1, 3072, f2w + (size_t)L * 768 * 3072, 0, 0, 1, 3072, 1,
           h, 0, 0, 1, 768, f2b + lC, g2 + lC, M, 768, 3072, 1.f, 0, 0, 1);
    }

    // ---- 2 class-attention blocks -----------------------------------------
    k_bcast_cls<<<48, 256, 0, stream>>>(cls_tok, cls);
    const int Mu = B_ * 197;         // 3152
    for (int t = 0; t < 2; t++) {
        size_t tC = (size_t)t * C_;
        size_t tCC = (size_t)t * 768 * 768;
        size_t tFC = (size_t)t * 3072 * 768;
        k_ln_cat<<<Mu, 256, 0, stream>>>(cls, h, tn1w + tC, tn1b + tC, u);
        mg(u, 0, 0, 1, 197 * 768, tqw + tCC, 0, 0, 1, 768, 1,
           qbuf, 0, 0, 1, 768, tqb + tC, nullptr, B_, 768, 768, 1.f, 0, 0, 1);
        mg(u, 0, 0, 1, 768, tkw + tCC, 0, 0, 1, 768, 1,
           kbuf, 0, 0, 1, 768, tkb + tC, nullptr, Mu, 768, 768, 1.f, 0, 1, 1);
        mg(u, 0, 0, 1, 768, tvw + tCC, 0, 0, 1, 768, 1,
           vbuf, 0, 0, 1, 768, tvb + tC, nullptr, Mu, 768, 768, 1.f, 0, 1, 1);
        k_ca_attn<<<B_ * H_, 256, 0, stream>>>(qbuf, kbuf, vbuf, ca_o);
        // cls += tg1 * (ca_o @ tprojw^T + tprojb)
        mg(ca_o, 0, 0, 1, 768, tprojw + tCC, 0, 0, 1, 768, 1,
           cls, 0, 0, 1, 768, tprojb + tC, tg1 + tC, B_, 768, 768, 1.f, 0, 0, 1);
        k_ln<<<B_, 256, 0, stream>>>(cls, tn2w + tC, tn2b + tC, clsB);
        mg(clsB, 0, 0, 1, 768, tf1w + tFC, 0, 0, 1, 768, 1,
           cmlp, 0, 0, 1, 3072, tf1b + (size_t)t * 3072, nullptr,
           B_, 3072, 768, 1.f, 1, 1, 1);
        // cls += tg2 * (cmlp @ tf2w^T + tf2b)
        mg(cmlp, 0, 0, 1, 3072, tf2w + tFC, 0, 0, 1, 3072, 1,
           cls, 0, 0, 1, 768, tf2b + tC, tg2 + tC, B_, 768, 3072, 1.f, 0, 0, 1);
    }

    // ---- final LN (cls only) + head directly to d_out (fp32) --------------
    k_ln<<<B_, 256, 0, stream>>>(cls, normw, normb, clsB);
    mg(clsB, 0, 0, 1, 768, headw, 0, 0, 1, 768, 1, d_out, 0, 0, 1, 1000,
       headb, nullptr, B_, 1000, 768, 1.f, 0, 0, 1);
}

// Round 2
// 4144.880 us; speedup vs baseline: 1.7755x; 1.7755x over previous
//
#include <hip/hip_runtime.h>
#include <hip/hip_bf16.h>

using bf16 = __hip_bfloat16;
typedef short short8 __attribute__((ext_vector_type(8)));
typedef float floatx4 __attribute__((ext_vector_type(4)));

#define B_   16
#define C_   768
#define NP_  196
#define H_   12
#define NPNP 38416   // 196*196

static __device__ __forceinline__ float b2f(bf16 v) { return __bfloat162float(v); }
static __device__ __forceinline__ unsigned short f2bfbits(float f) {
    bf16 t = __float2bfloat16(f);
    return *(unsigned short*)&t;
}

// ---------------------------------------------------------------------------
// Batched MFMA GEMM:  C[z][m][n] = act( scale * sum_k A[z][m][k]*W[z][n][k] + bias[n] )
// A bf16 row-major. W bf16 (WFP=0) or fp32 (WFP=1, converted to bf16 while
// staging). K multiple of 32, lda/ldw multiple of 8.
// Batch offsets two-level for A, W, C:  off = (z/BI)*so + (z%BI)*si.
// Epilogue: resg!=null -> C += resg[n]*v (fp32 RMW); else fp32/bf16 store.
// 256 thr = 4 waves arranged WM x WN; wave computes (BM/WM)x(BN/WN) via
// 16x16x32 MFMA. LDS double-buffered; register prefetch one k-step ahead;
// raw s_barrier + lgkmcnt-only waits so global loads stay in flight across
// the barrier (vmcnt never drained at a barrier).
// ---------------------------------------------------------------------------
template<int BM, int BN, int WM, int WN, int WFP>
__global__ __launch_bounds__(256)
void k_mgemm(const bf16* __restrict__ A, long long sAo, long long sAi, int ABI, int lda,
             const void* __restrict__ W, long long sWo, long long sWi, int WBI, int ldw,
             char* __restrict__ Cb, long long sCo, long long sCi, int CBI, int ldc,
             const float* __restrict__ bias, const float* __restrict__ resg,
             int M, int N, int K, float scale, int act, int outbf)
{
    constexpr int FM = BM / (16 * WM);
    constexpr int FN = BN / (16 * WN);
    constexpr int ACH = (BM * 4 + 255) / 256;   // 16B chunks per thread (A)
    constexpr int WCH = (BN * 4 + 255) / 256;   // chunks per thread (W)

    __shared__ unsigned short As[2 * BM * 40];  // row stride 40 elems (80B)
    __shared__ unsigned short Ws[2 * BN * 40];

    const int z = blockIdx.z;
    const long long aoff = (long long)(z / ABI) * sAo + (long long)(z % ABI) * sAi;
    const long long woff = (long long)(z / WBI) * sWo + (long long)(z % WBI) * sWi;
    const unsigned short* Ag = (const unsigned short*)A + aoff;

    const int tid = threadIdx.x;
    const int lane = tid & 63, w = tid >> 6;
    const int wm = w / WN, wn = w % WN;
    const int p = lane & 15, q = lane >> 4;
    const int bm = blockIdx.y * BM, bn = blockIdx.x * BN;

    short8  aR[ACH];
    short8  wR[WCH];
    floatx4 w0R[WCH], w1R[WCH];

    auto loadAB = [&](int k0) {
#pragma unroll
        for (int i = 0; i < ACH; i++) {
            int c = tid + 256 * i;
            if (c < BM * 4) {
                int r = c >> 2, off = (c & 3) * 8;
                int am = bm + r; am = (am < M) ? am : (M - 1);
                aR[i] = *(const short8*)(Ag + (size_t)am * lda + k0 + off);
            }
        }
#pragma unroll
        for (int i = 0; i < WCH; i++) {
            int c = tid + 256 * i;
            if (c < BN * 4) {
                int r = c >> 2, off = (c & 3) * 8;
                int wr = bn + r; wr = (wr < N) ? wr : (N - 1);
                if constexpr (WFP) {
                    const float* wp = (const float*)W + woff + (size_t)wr * ldw + k0 + off;
                    w0R[i] = *(const floatx4*)wp;
                    w1R[i] = *(const floatx4*)(wp + 4);
                } else {
                    wR[i] = *(const short8*)((const unsigned short*)W + woff
                                             + (size_t)wr * ldw + k0 + off);
                }
            }
        }
    };

    auto storeLDS = [&](int buf) {
        unsigned short* Ab = As + buf * (BM * 40);
        unsigned short* Wb = Ws + buf * (BN * 40);
#pragma unroll
        for (int i = 0; i < ACH; i++) {
            int c = tid + 256 * i;
            if (c < BM * 4) {
                int r = c >> 2, off = (c & 3) * 8;
                *(short8*)(&Ab[r * 40 + off]) = aR[i];
            }
        }
#pragma unroll
        for (int i = 0; i < WCH; i++) {
            int c = tid + 256 * i;
            if (c < BN * 4) {
                int r = c >> 2, off = (c & 3) * 8;
                if constexpr (WFP) {
                    unsigned short* d = &Wb[r * 40 + off];
#pragma unroll
                    for (int j = 0; j < 4; j++) d[j]     = f2bfbits(w0R[i][j]);
#pragma unroll
                    for (int j = 0; j < 4; j++) d[4 + j] = f2bfbits(w1R[i][j]);
                } else {
                    *(short8*)(&Wb[r * 40 + off]) = wR[i];
                }
            }
        }
    };

    floatx4 acc[FM][FN] = {};

    loadAB(0);
    storeLDS(0);
    if (32 < K) loadAB(32);
    asm volatile("s_waitcnt lgkmcnt(0)" ::: "memory");
    __builtin_amdgcn_s_barrier();

    int cur = 0;
    for (int k0 = 0; k0 < K; k0 += 32) {
        const unsigned short* Ab = As + cur * (BM * 40);
        const unsigned short* Wb = Ws + cur * (BN * 40);
        short8 af[FM], wf[FN];
#pragma unroll
        for (int i = 0; i < FM; i++)
            af[i] = *(const short8*)(&Ab[(wm * (BM / WM) + i * 16 + p) * 40 + q * 8]);
#pragma unroll
        for (int j = 0; j < FN; j++)
            wf[j] = *(const short8*)(&Wb[(wn * (BN / WN) + j * 16 + p) * 40 + q * 8]);
        __builtin_amdgcn_s_setprio(1);
#pragma unroll
        for (int i = 0; i < FM; i++)
#pragma unroll
            for (int j = 0; j < FN; j++)
                acc[i][j] = __builtin_amdgcn_mfma_f32_16x16x32_bf16(af[i], wf[j], acc[i][j], 0, 0, 0);
        __builtin_amdgcn_s_setprio(0);
        if (k0 + 32 < K) {
            storeLDS(cur ^ 1);                 // auto vmcnt wait on prefetch regs
            if (k0 + 64 < K) loadAB(k0 + 64);  // issue next; stays in flight
            asm volatile("s_waitcnt lgkmcnt(0)" ::: "memory");
            __builtin_amdgcn_s_barrier();
        }
        cur ^= 1;
    }

    const long long coff = (long long)(z / CBI) * sCo + (long long)(z % CBI) * sCi;
    float* Cf = (float*)Cb + coff;
    bf16*  Ch = (bf16*)Cb + coff;
#pragma unroll
    for (int i = 0; i < FM; i++) {
#pragma unroll
        for (int r = 0; r < 4; r++) {
            int gm = bm + wm * (BM / WM) + i * 16 + q * 4 + r;
            if (gm >= M) continue;
#pragma unroll
            for (int j = 0; j < FN; j++) {
                int gn = bn + wn * (BN / WN) + j * 16 + p;
                if (gn >= N) continue;
                float v = acc[i][j][r] * scale;
                if (bias) v += bias[gn];
                if (act) v = 0.5f * v * (1.0f + erff(v * 0.70710678118654752f));
                if (resg)       Cf[(size_t)gm * ldc + gn] += resg[gn] * v;
                else if (outbf) Ch[(size_t)gm * ldc + gn] = __float2bfloat16(v);
                else            Cf[(size_t)gm * ldc + gn] = v;
            }
        }
    }
}

// ---------------------------------------------------------------------------
__global__ __launch_bounds__(256)
void k_patch_gather(const float* __restrict__ x, bf16* __restrict__ p)
{
    int idx = blockIdx.x * 256 + threadIdx.x;            // 2,408,448
    int k = idx % 768;
    int n = (idx / 768) % NP_;
    int b = idx / (768 * NP_);
    int c = k >> 8, r = k & 255;
    int py = r >> 4, px = r & 15;
    int gy = n / 14, gx = n % 14;
    p[idx] = __float2bfloat16(x[(((size_t)b * 3 + c) * 224 + gy * 16 + py) * 224 + gx * 16 + px]);
}

__global__ __launch_bounds__(256)
void k_addpos(float* __restrict__ h, const float* __restrict__ pos)
{
    int idx = blockIdx.x * 256 + threadIdx.x;            // 2,408,448
    h[idx] += pos[idx % (NP_ * C_)];
}

// LayerNorm over C=768: fp32 in -> bf16 out. One block per row.
__device__ __forceinline__ void ln_row(const float* __restrict__ x,
                                       const float* __restrict__ w,
                                       const float* __restrict__ b,
                                       bf16* __restrict__ y, int t,
                                       float* red, float* stat)
{
    float a0 = x[t], a1 = x[t + 256], a2 = x[t + 512];
    float s = a0 + a1 + a2;
#pragma unroll
    for (int off = 32; off > 0; off >>= 1) s += __shfl_down(s, off);
    if ((t & 63) == 0) red[t >> 6] = s;
    __syncthreads();
    if (t == 0) stat[0] = (red[0] + red[1] + red[2] + red[3]) * (1.f / 768.f);
    __syncthreads();
    float m = stat[0];
    float d0 = a0 - m, d1 = a1 - m, d2 = a2 - m;
    float s2 = d0 * d0 + d1 * d1 + d2 * d2;
#pragma unroll
    for (int off = 32; off > 0; off >>= 1) s2 += __shfl_down(s2, off);
    if ((t & 63) == 0) red[t >> 6] = s2;
    __syncthreads();
    if (t == 0) stat[1] = rsqrtf((red[0] + red[1] + red[2] + red[3]) * (1.f / 768.f) + 1e-6f);
    __syncthreads();
    float r = stat[1];
    y[t]       = __float2bfloat16(d0 * r * w[t]       + b[t]);
    y[t + 256] = __float2bfloat16(d1 * r * w[t + 256] + b[t + 256]);
    y[t + 512] = __float2bfloat16(d2 * r * w[t + 512] + b[t + 512]);
}

__global__ __launch_bounds__(256)
void k_ln(const float* __restrict__ X, const float* __restrict__ w,
          const float* __restrict__ b, bf16* __restrict__ Y)
{
    __shared__ float red[4];
    __shared__ float stat[2];
    int row = blockIdx.x;
    ln_row(X + (size_t)row * C_, w, b, Y + (size_t)row * C_, threadIdx.x, red, stat);
}

__global__ __launch_bounds__(256)
void k_ln_cat(const float* __restrict__ cls, const float* __restrict__ h,
              const float* __restrict__ w, const float* __restrict__ b,
              bf16* __restrict__ Y)
{
    __shared__ float red[4];
    __shared__ float stat[2];
    int row = blockIdx.x;
    int bb = row / 197, tkn = row % 197;
    const float* src = (tkn == 0) ? (cls + (size_t)bb * C_)
                                  : (h + ((size_t)bb * NP_ + (tkn - 1)) * C_);
    ln_row(src, w, b, Y + (size_t)row * C_, threadIdx.x, red, stat);
}

// V transposed: VT[z][d][m] (m padded 196->224 with 0)
__global__ __launch_bounds__(256)
void k_splitv(const bf16* __restrict__ qkv, bf16* __restrict__ VT)
{
    int idx = blockIdx.x * 256 + threadIdx.x;            // 2,752,512
    int m = idx % 224;
    int rest = idx / 224;
    int d = rest & 63, zz = rest >> 6;
    int b = zz / H_, hh = zz % H_;
    bf16 v = __float2bfloat16(0.f);
    if (m < NP_) v = qkv[((size_t)b * NP_ + m) * 2304 + 1536 + hh * 64 + d];
    VT[idx] = v;
}

// ---------------------------------------------------------------------------
// Fused pre-mix + softmax + post-mix (reads S once, writes P bf16 [z][196][224])
// One block per (b, n): 3136 blocks x 256 threads, thread = column m.
// ---------------------------------------------------------------------------
__global__ __launch_bounds__(256)
void k_attn_mix(const float* __restrict__ S, const float* __restrict__ plw,
                const float* __restrict__ plb, const float* __restrict__ pww,
                const float* __restrict__ pwb, bf16* __restrict__ P)
{
    __shared__ float wpre[144], wpost[144], bpre[12], bpost[12];
    __shared__ float red[4][12];
    int tid = threadIdx.x;
    if (tid < 144) { wpre[tid] = plw[tid]; wpost[tid] = pww[tid]; }
    if (tid < 12)  { bpre[tid] = plb[tid]; bpost[tid] = pwb[tid]; }
    __syncthreads();
    int b = blockIdx.x / NP_, n = blockIdx.x % NP_;
    int m = tid;
    bool on = (m < NP_);
    const float* p0 = S + ((size_t)b * H_ * NP_ + n) * NP_ + (on ? m : 0);
    float v[12];
#pragma unroll
    for (int h = 0; h < 12; h++) v[h] = p0[(size_t)h * NPNP];
    float s[12];
#pragma unroll
    for (int g = 0; g < 12; g++) {
        float a = bpre[g];
#pragma unroll
        for (int h = 0; h < 12; h++) a += wpre[g * 12 + h] * v[h];
        s[g] = on ? a : -1e30f;
    }
    int wv = tid >> 6, ln = tid & 63;
    float mx[12];
#pragma unroll
    for (int g = 0; g < 12; g++) {
        float x = s[g];
#pragma unroll
        for (int off = 32; off > 0; off >>= 1) x = fmaxf(x, __shfl_down(x, off));
        mx[g] = x;
    }
    if (ln == 0) {
#pragma unroll
        for (int g = 0; g < 12; g++) red[wv][g] = mx[g];
    }
    __syncthreads();
#pragma unroll
    for (int g = 0; g < 12; g++)
        mx[g] = fmaxf(fmaxf(red[0][g], red[1][g]), fmaxf(red[2][g], red[3][g]));
    __syncthreads();
    float e[12], sm[12];
#pragma unroll
    for (int g = 0; g < 12; g++) {
        e[g] = on ? expf(s[g] - mx[g]) : 0.f;
        float x = e[g];
#pragma unroll
        for (int off = 32; off > 0; off >>= 1) x += __shfl_down(x, off);
        sm[g] = x;
    }
    if (ln == 0) {
#pragma unroll
        for (int g = 0; g < 12; g++) red[wv][g] = sm[g];
    }
    __syncthreads();
#pragma unroll
    for (int g = 0; g < 12; g++) {
        float t = (red[0][g] + red[1][g]) + (red[2][g] + red[3][g]);
        e[g] *= 1.0f / t;
    }
    if (on) {
        size_t base = ((size_t)b * H_ * NP_ + n) * 224 + m;
#pragma unroll
        for (int g = 0; g < 12; g++) {
            float a = bpost[g];
#pragma unroll
            for (int h = 0; h < 12; h++) a += wpost[g * 12 + h] * e[h];
            P[base + (size_t)g * NP_ * 224] = __float2bfloat16(a);
        }
    }
}

// class-attention: q fp32 [B,C], k/v bf16 [B*197,C] -> o bf16 [B,C]
__global__ __launch_bounds__(256)
void k_ca_attn(const float* __restrict__ q, const bf16* __restrict__ kb,
               const bf16* __restrict__ vb, bf16* __restrict__ o)
{
    __shared__ float sc[200];
    __shared__ float qs[64];
    __shared__ float inv_s;
    int b = blockIdx.x / H_, hh = blockIdx.x % H_;
    int t = threadIdx.x;
    if (t < 64) qs[t] = q[b * C_ + hh * 64 + t] * 0.125f;
    __syncthreads();
    if (t < 197) {
        const bf16* kp = kb + ((size_t)b * 197 + t) * C_ + hh * 64;
        float s = 0.f;
#pragma unroll 8
        for (int d = 0; d < 64; d++) s += qs[d] * b2f(kp[d]);
        sc[t] = s;
    }
    __syncthreads();
    if (t == 0) {
        float mx = -1e30f;
        for (int m = 0; m < 197; m++) mx = fmaxf(mx, sc[m]);
        float sum = 0.f;
        for (int m = 0; m < 197; m++) { float e = expf(sc[m] - mx); sc[m] = e; sum += e; }
        inv_s = 1.0f / sum;
    }
    __syncthreads();
    if (t < 64) {
        const bf16* vp = vb + (size_t)b * 197 * C_ + hh * 64 + t;
        float acc = 0.f;
        for (int m = 0; m < 197; m++) acc += sc[m] * b2f(vp[(size_t)m * C_]);
        o[b * C_ + hh * 64 + t] = __float2bfloat16(acc * inv_s);
    }
}

__global__ __launch_bounds__(256)
void k_bcast_cls(const float* __restrict__ ct, float* __restrict__ cls)
{
    int i = blockIdx.x * 256 + threadIdx.x;              // 12288
    if (i < B_ * C_) cls[i] = ct[i % C_];
}

__global__ __launch_bounds__(256)
void k_zero(float* __restrict__ p, int n)
{
    int i = blockIdx.x * 256 + threadIdx.x;
    if (i < n) p[i] = 0.f;
}

// ---------------------------------------------------------------------------
extern "C" void kernel_launch(void* const* d_in, const int* in_sizes, int n_in,
                              void* d_out, int out_size, void* d_ws, size_t ws_size,
                              hipStream_t stream)
{
    const float* in_x    = (const float*)d_in[0];
    const float* patch_w = (const float*)d_in[1];
    const float* patch_b = (const float*)d_in[2];
    const float* cls_tok = (const float*)d_in[3];
    const float* pos_emb = (const float*)d_in[4];
    const float* n1w = (const float*)d_in[5],  *n1b = (const float*)d_in[6];
    const float* qkvw = (const float*)d_in[7], *qkvb = (const float*)d_in[8];
    const float* plw = (const float*)d_in[9],  *plb = (const float*)d_in[10];
    const float* pww = (const float*)d_in[11], *pwb = (const float*)d_in[12];
    const float* projw = (const float*)d_in[13], *projb = (const float*)d_in[14];
    const float* n2w = (const float*)d_in[15], *n2b = (const float*)d_in[16];
    const float* f1w = (const float*)d_in[17], *f1b = (const float*)d_in[18];
    const float* f2w = (const float*)d_in[19], *f2b = (const float*)d_in[20];
    const float* g1 = (const float*)d_in[21],  *g2 = (const float*)d_in[22];
    const float* tn1w = (const float*)d_in[23], *tn1b = (const float*)d_in[24];
    const float* tqw = (const float*)d_in[25], *tqb = (const float*)d_in[26];
    const float* tkw = (const float*)d_in[27], *tkb = (const float*)d_in[28];
    const float* tvw = (const float*)d_in[29], *tvb = (const float*)d_in[30];
    const float* tprojw = (const float*)d_in[31], *tprojb = (const float*)d_in[32];
    const float* tn2w = (const float*)d_in[33], *tn2b = (const float*)d_in[34];
    const float* tf1w = (const float*)d_in[35], *tf1b = (const float*)d_in[36];
    const float* tf2w = (const float*)d_in[37], *tf2b = (const float*)d_in[38];
    const float* tg1 = (const float*)d_in[39], *tg2 = (const float*)d_in[40];
    const float* normw = (const float*)d_in[41], *normb = (const float*)d_in[42];
    const float* headw = (const float*)d_in[43], *headb = (const float*)d_in[44];
    (void)in_sizes; (void)n_in; (void)out_size; (void)ws_size;

    const int M = B_ * NP_;          // 3136
    char* wsb = (char*)d_ws;
    // ---- workspace layout (bytes) ----
    float* h    = (float*)(wsb + 0);                 //  9,633,792 B fp32 residual
    bf16*  yB   = (bf16*)(wsb + 9633792);            //  4,816,896 B bf16 LN out
    char*  BIG  = wsb + 14450688;                    // 29,503,488 B multi-use
    bf16*  VT   = (bf16*)(wsb + 53587968);           //  5,505,024
    bf16*  P    = (bf16*)(wsb + 59092992);           // 16,859,136
    bf16*  oB   = (bf16*)(wsb + 75952128);           //  4,816,896 -> end 80,769,024
    // BIG aliases
    bf16*  pbuf = (bf16*)BIG;                        // patches [3136x768]
    bf16*  qkvB = (bf16*)BIG;                        // [3136x2304] bf16
    float* S    = (float*)BIG;                       // [192][196][196] fp32
    bf16*  hidB = (bf16*)BIG;                        // [3136x3072] bf16
    // class-attention aliases
    bf16*  u    = (bf16*)BIG;                        // [3152x768]
    bf16*  kbuf = (bf16*)(BIG + 5242880);
    bf16*  vbuf = (bf16*)(BIG + 10485760);
    float* qbuf = (float*)(wsb + 43954176);          // 49,152
    bf16*  ca_o = (bf16*)(wsb + 43954176 + 65536);
    bf16*  clsB = (bf16*)(wsb + 43954176 + 262144);
    bf16*  cmlp = (bf16*)(wsb + 43954176 + 327680);
    float* cls  = (float*)(wsb + 59092992);          // alias P (dead in CA phase)

    auto mg = [&](int tm, int tn,
                  const bf16* A, long long sAo, long long sAi, int ABI, int lda,
                  const void* Wt, long long sWo, long long sWi, int WBI, int ldw, int wfp,
                  void* Cc, long long sCo, long long sCi, int CBI, int ldc,
                  const float* bias, const float* resg, int Mm, int Nn, int Kk,
                  float scale, int act, int outbf, int batch) {
        dim3 g((Nn + tn - 1) / tn, (Mm + tm - 1) / tm, batch);
#define MGARGS A, sAo, sAi, ABI, lda, Wt, sWo, sWi, WBI, ldw, (char*)Cc, sCo, sCi, CBI, ldc, \
               bias, resg, Mm, Nn, Kk, scale, act, outbf
        if      (tm == 128 && tn == 128 && !wfp) k_mgemm<128,128,2,2,0><<<g,256,0,stream>>>(MGARGS);
        else if (tm ==  64 && tn == 128 &&  wfp) k_mgemm< 64,128,2,2,1><<<g,256,0,stream>>>(MGARGS);
        else if (tm ==  64 && tn ==  64 &&  wfp) k_mgemm< 64, 64,2,2,1><<<g,256,0,stream>>>(MGARGS);
        else if (tm ==  64 && tn ==  64 && !wfp) k_mgemm< 64, 64,2,2,0><<<g,256,0,stream>>>(MGARGS);
        else if (tm ==  16 && tn == 128 &&  wfp) k_mgemm< 16,128,1,4,1><<<g,256,0,stream>>>(MGARGS);
#undef MGARGS
    };

    // zero P once (tail columns 196..223 must be 0; ws re-poisoned every call)
    k_zero<<<(4214784 + 255) / 256, 256, 0, stream>>>((float*)P, 4214784);

    // ---- patch embed -------------------------------------------------------
    k_patch_gather<<<9408, 256, 0, stream>>>(in_x, pbuf);
    mg(64, 64, pbuf, 0, 0, 1, 768, patch_w, 0, 0, 1, 768, 1, h, 0, 0, 1, 768,
       patch_b, nullptr, M, 768, 768, 1.f, 0, 0, 1);
    k_addpos<<<9408, 256, 0, stream>>>(h, pos_emb);

    // ---- 12 talking-heads blocks ------------------------------------------
    for (int L = 0; L < 12; L++) {
        size_t lC = (size_t)L * C_;
        k_ln<<<M, 256, 0, stream>>>(h, n1w + lC, n1b + lC, yB);
        mg(64, 128, yB, 0, 0, 1, 768, qkvw + (size_t)L * 2304 * 768, 0, 0, 1, 768, 1,
           qkvB, 0, 0, 1, 2304, qkvb + (size_t)L * 2304, nullptr,
           M, 2304, 768, 1.f, 0, 1, 1);
        k_splitv<<<10752, 256, 0, stream>>>(qkvB, VT);
        // S[z] = 0.125 * Q[z] @ K[z]^T  directly from qkvB (z = b*12+h)
        mg(128, 128, qkvB, (long long)NP_ * 2304, 64, H_, 2304,
           qkvB + 768, (long long)NP_ * 2304, 64, H_, 2304, 0,
           S, NPNP, 0, 1, 196, nullptr, nullptr,
           196, 196, 64, 0.125f, 0, 0, 192);
        // fused pre-mix + softmax + post-mix -> P bf16 [z][196][224]
        k_attn_mix<<<M, 256, 0, stream>>>(S, plw + L * 144, plb + L * 12,
                                          pww + L * 144, pwb + L * 12, P);
        // o[b][n][h*64+d] = P[z] @ V[z]  (K=224 zero-padded)
        mg(64, 64, P, 43904, 0, 1, 224, VT, 14336, 0, 1, 224, 0,
           oB, 150528, 64, H_, 768, nullptr, nullptr,
           196, 64, 224, 1.f, 0, 1, 192);
        // proj with fused residual: h += g1 * (oB @ projw^T + projb)
        mg(64, 64, oB, 0, 0, 1, 768, projw + (size_t)L * 768 * 768, 0, 0, 1, 768, 1,
           h, 0, 0, 1, 768, projb + lC, g1 + lC, M, 768, 768, 1.f, 0, 0, 1);
        k_ln<<<M, 256, 0, stream>>>(h, n2w + lC, n2b + lC, yB);
        mg(64, 128, yB, 0, 0, 1, 768, f1w + (size_t)L * 3072 * 768, 0, 0, 1, 768, 1,
           hidB, 0, 0, 1, 3072, f1b + (size_t)L * 3072, nullptr,
           M, 3072, 768, 1.f, 1, 1, 1);
        // f2 with fused residual: h += g2 * (hidB @ f2w^T + f2b)
        mg(64, 64, hidB, 0, 0, 1, 3072, f2w + (size_t)L * 768 * 3072, 0, 0, 1, 3072, 1,
           h, 0, 0, 1, 768, f2b + lC, g2 + lC, M, 768, 3072, 1.f, 0, 0, 1);
    }

    // ---- 2 class-attention blocks -----------------------------------------
    k_bcast_cls<<<48, 256, 0, stream>>>(cls_tok, cls);
    const int Mu = B_ * 197;         // 3152
    for (int t = 0; t < 2; t++) {
        size_t tC = (size_t)t * C_;
        size_t tCC = (size_t)t * 768 * 768;
        size_t tFC = (size_t)t * 3072 * 768;
        k_ln_cat<<<Mu, 256, 0, stream>>>(cls, h, tn1w + tC, tn1b + tC, u);
        mg(16, 128, u, 0, 0, 1, 197 * 768, tqw + tCC, 0, 0, 1, 768, 1,
           qbuf, 0, 0, 1, 768, tqb + tC, nullptr, B_, 768, 768, 1.f, 0, 0, 1);
        mg(64, 64, u, 0, 0, 1, 768, tkw + tCC, 0, 0, 1, 768, 1,
           kbuf, 0, 0, 1, 768, tkb + tC, nullptr, Mu, 768, 768, 1.f, 0, 1, 1);
        mg(64, 64, u, 0, 0, 1, 768, tvw + tCC, 0, 0, 1, 768, 1,
           vbuf, 0, 0, 1, 768, tvb + tC, nullptr, Mu, 768, 768, 1.f, 0, 1, 1);
        k_ca_attn<<<B_ * H_, 256, 0, stream>>>(qbuf, kbuf, vbuf, ca_o);
        // cls += tg1 * (ca_o @ tprojw^T + tprojb)
        mg(16, 128, ca_o, 0, 0, 1, 768, tprojw + tCC, 0, 0, 1, 768, 1,
           cls, 0, 0, 1, 768, tprojb + tC, tg1 + tC, B_, 768, 768, 1.f, 0, 0, 1);
        k_ln<<<B_, 256, 0, stream>>>(cls, tn2w + tC, tn2b + tC, clsB);
        mg(16, 128, clsB, 0, 0, 1, 768, tf1w + tFC, 0, 0, 1, 768, 1,
           cmlp, 0, 0, 1, 3072, tf1b + (size_t)t * 3072, nullptr,
           B_, 3072, 768, 1.f, 1, 1, 1);
        // cls += tg2 * (cmlp @ tf2w^T + tf2b)
        mg(16, 128, cmlp, 0, 0, 1, 3072, tf2w + tFC, 0, 0, 1, 3072, 1,
           cls, 0, 0, 1, 768, tf2b + tC, tg2 + tC, B_, 768, 3072, 1.f, 0, 0, 1);
    }

    // ---- final LN (cls only) + head directly to d_out (fp32) --------------
    k_ln<<<B_, 256, 0, stream>>>(cls, normw, normb, clsB);
    mg(16, 128, clsB, 0, 0, 1, 768, headw, 0, 0, 1, 768, 1, d_out, 0, 0, 1, 1000,
       headb, nullptr, B_, 1000, 768, 1.f, 0, 0, 1);
}